// Round 11
// baseline (83.354 us; speedup 1.0000x reference)
//
#include <hip/hip_runtime.h>
#include <hip/hip_bf16.h>

#define Bv 8
#define Nv 512
#define Dv 1024
#define Ev 8
#define Hv 8
#define HDv 128
#define EPSv 1e-5f

typedef __attribute__((ext_vector_type(8))) short short8;
typedef __attribute__((ext_vector_type(4))) float f32x4;

__device__ __forceinline__ unsigned short f2b(float f) {
    __hip_bfloat16 h = __float2bfloat16(f);
    return *reinterpret_cast<unsigned short*>(&h);
}
__device__ __forceinline__ float bf2f(unsigned int u) {
    union { unsigned int i; float f; } v; v.i = u << 16; return v.f;
}
__device__ __forceinline__ unsigned int blend2(unsigned int a, unsigned int b,
                                               float tw0, float tw1) {
    float lo = tw0 * bf2f(a & 0xffffu) + tw1 * bf2f(b & 0xffffu);
    float hi = tw0 * bf2f(a >> 16)     + tw1 * bf2f(b >> 16);
    return (unsigned int)f2b(lo) | ((unsigned int)f2b(hi) << 16);
}

// async global->LDS, 16 bytes per lane; LDS dest must be linear (base + lane*16)
__device__ __forceinline__ void gld16(const void* g, void* l) {
    __builtin_amdgcn_global_load_lds(
        (const __attribute__((address_space(1))) void*)(uintptr_t)(g),
        (__attribute__((address_space(3))) void*)(uintptr_t)(l), 16, 0, 0);
}

// ---------------- fused kernel 1: everything hides under the weight stream --
//   blocks [0,256):     gemm1 (xp = x @ in_w^T + in_b), reg-staged f32->bf16
//                       operands (no pre-cast pass), MODE2 epilogue:
//                       transposed bf16 out (xpT) + per-(b,d) LN partials
//   blocks [256,384):   x column raw sums -> atomicAdd into xmean (pre-zeroed)
//   blocks [384,1408):  weight-row softmax -> wa bf16 (8 rows/wave, no-max exp)
//   blocks [1408,1536): cast out_w -> bf16
__global__ __launch_bounds__(256) void k_fused1(
    const float* __restrict__ x,        // [8][512][1024] f32
    const float* __restrict__ w1,       // in_w [1024][1024] f32
    const float* __restrict__ weight,   // [32768][512] f32
    const float* __restrict__ w2,       // out_w [1024][1024] f32
    const float* __restrict__ in_b,     // [1024] f32
    unsigned short* __restrict__ xpT,   // [8][1024][512] bf16 out (transposed)
    float2* __restrict__ part,          // LN partials
    float* __restrict__ xmean,          // [8][1024] f32, raw col sums (atomic)
    unsigned short* __restrict__ wa,    // [32768][512] bf16 softmaxed
    unsigned short* __restrict__ w2b) { // out_w bf16
    __shared__ __align__(16) unsigned short sh[21504];  // 42 KB
    const int bid = blockIdx.x;
    const int t = threadIdx.x;

    if (bid >= 256) {
        if (bid < 384) {
            // x column raw sums (32 rows per block, coalesced float4 rows)
            int xb2 = bid - 256;
            int b = xb2 >> 4, c = xb2 & 15;
            const float* px = x + ((size_t)b * Nv + c * 32) * Dv + t * 4;
            float4 s4 = make_float4(0.f, 0.f, 0.f, 0.f);
            #pragma unroll 8
            for (int r = 0; r < 32; ++r) {
                float4 v = *(const float4*)(px + (size_t)r * Dv);
                s4.x += v.x; s4.y += v.y; s4.z += v.z; s4.w += v.w;
            }
            float* xm = xmean + b * Dv + t * 4;
            atomicAdd(xm + 0, s4.x); atomicAdd(xm + 1, s4.y);
            atomicAdd(xm + 2, s4.z); atomicAdd(xm + 3, s4.w);
            return;
        }
        if (bid < 1408) {
            // weight softmax: 8 rows/wave, contiguous 1KB spans, no-max exp
            // (|w| <= 1/sqrt(512) so exp in [0.957, 1.045])
            int lane = t & 63;
            int r0 = (((bid - 384) * 4) + (t >> 6)) * 8;
            const float* wp = weight + (size_t)r0 * Nv + lane * 4;
            float v[8][8];
            #pragma unroll
            for (int r = 0; r < 8; ++r) {
                float4 a = *(const float4*)(wp + (size_t)r * Nv);
                float4 b = *(const float4*)(wp + (size_t)r * Nv + 256);
                v[r][0] = a.x; v[r][1] = a.y; v[r][2] = a.z; v[r][3] = a.w;
                v[r][4] = b.x; v[r][5] = b.y; v[r][6] = b.z; v[r][7] = b.w;
            }
            float sm[8];
            #pragma unroll
            for (int r = 0; r < 8; ++r) {
                #pragma unroll
                for (int i = 0; i < 8; ++i) v[r][i] = __expf(v[r][i]);
                float s01 = v[r][0] + v[r][1], s23 = v[r][2] + v[r][3];
                float s45 = v[r][4] + v[r][5], s67 = v[r][6] + v[r][7];
                sm[r] = (s01 + s23) + (s45 + s67);
            }
            for (int off = 1; off < 64; off <<= 1) {
                #pragma unroll
                for (int r = 0; r < 8; ++r) sm[r] += __shfl_xor(sm[r], off);
            }
            unsigned short* wq = wa + (size_t)r0 * Nv + lane * 4;
            #pragma unroll
            for (int r = 0; r < 8; ++r) {
                float inv = 1.f / sm[r];
                uint2 p0, p1;
                p0.x = (unsigned)f2b(v[r][0] * inv) | ((unsigned)f2b(v[r][1] * inv) << 16);
                p0.y = (unsigned)f2b(v[r][2] * inv) | ((unsigned)f2b(v[r][3] * inv) << 16);
                p1.x = (unsigned)f2b(v[r][4] * inv) | ((unsigned)f2b(v[r][5] * inv) << 16);
                p1.y = (unsigned)f2b(v[r][6] * inv) | ((unsigned)f2b(v[r][7] * inv) << 16);
                *(uint2*)(wq + (size_t)r * Nv) = p0;
                *(uint2*)(wq + (size_t)r * Nv + 256) = p1;
            }
            return;
        }
        // out_w cast
        int base = (bid - 1408) * 8192;
        #pragma unroll
        for (int i = 0; i < 8; ++i) {
            float4 a = *(const float4*)(w2 + base + i * 1024 + t * 4);
            uint2 p;
            p.x = (unsigned)f2b(a.x) | ((unsigned)f2b(a.y) << 16);
            p.y = (unsigned)f2b(a.z) | ((unsigned)f2b(a.w) << 16);
            *(uint2*)(w2b + base + i * 1024 + t * 4) = p;
        }
        return;
    }

    // ---- gemm1: reg-staged f32 operands -> bf16 LDS (single buffer) ----
    unsigned short* sAs = sh;            // [128*64] bf16 A tile (16 KB)
    unsigned short* sBs = sh + 8192;     // [128*64] bf16 W tile (16 KB)
    const int bn = (bid & 7) * 128;
    const int bm = (bid >> 3) * 128;
    const int lane = t & 63;
    const int w = t >> 6, wm = w >> 1, wn = w & 1;
    const int fr = lane & 15, fq = lane >> 4;
    f32x4 acc[4][4] = {};
    float4 rx[4][2], rw4[4][2];

#define GLOADF(k0)                                                          \
    {                                                                       \
        _Pragma("unroll")                                                   \
        for (int i_ = 0; i_ < 4; ++i_) {                                    \
            int c_ = t + i_ * 256;                                          \
            int row_ = c_ >> 3, col_ = c_ & 7;                              \
            int cs_ = col_ ^ (row_ & 7);                                    \
            const float* pa_ = x + (size_t)(bm + row_) * Dv + (k0) + cs_ * 8;  \
            rx[i_][0] = *(const float4*)pa_;                                \
            rx[i_][1] = *(const float4*)(pa_ + 4);                          \
            const float* pw_ = w1 + (size_t)(bn + row_) * Dv + (k0) + cs_ * 8; \
            rw4[i_][0] = *(const float4*)pw_;                               \
            rw4[i_][1] = *(const float4*)(pw_ + 4);                         \
        }                                                                   \
    }
#define PACKST()                                                            \
    {                                                                       \
        _Pragma("unroll")                                                   \
        for (int i_ = 0; i_ < 4; ++i_) {                                    \
            int c_ = t + i_ * 256;                                          \
            uint4 pa_, pw_;                                                 \
            pa_.x = (unsigned)f2b(rx[i_][0].x) | ((unsigned)f2b(rx[i_][0].y) << 16); \
            pa_.y = (unsigned)f2b(rx[i_][0].z) | ((unsigned)f2b(rx[i_][0].w) << 16); \
            pa_.z = (unsigned)f2b(rx[i_][1].x) | ((unsigned)f2b(rx[i_][1].y) << 16); \
            pa_.w = (unsigned)f2b(rx[i_][1].z) | ((unsigned)f2b(rx[i_][1].w) << 16); \
            pw_.x = (unsigned)f2b(rw4[i_][0].x) | ((unsigned)f2b(rw4[i_][0].y) << 16); \
            pw_.y = (unsigned)f2b(rw4[i_][0].z) | ((unsigned)f2b(rw4[i_][0].w) << 16); \
            pw_.z = (unsigned)f2b(rw4[i_][1].x) | ((unsigned)f2b(rw4[i_][1].y) << 16); \
            pw_.w = (unsigned)f2b(rw4[i_][1].z) | ((unsigned)f2b(rw4[i_][1].w) << 16); \
            *(uint4*)&sAs[c_ * 8] = pa_;                                    \
            *(uint4*)&sBs[c_ * 8] = pw_;                                    \
        }                                                                   \
    }

    GLOADF(0);
    for (int it = 0; it < 16; ++it) {
        PACKST();                       // consumes regs loaded last iter
        if (it + 1 < 16) GLOADF((it + 1) * 64);   // in flight across MFMA
        asm volatile("s_waitcnt lgkmcnt(0)" ::: "memory");
        __builtin_amdgcn_s_barrier();
        #pragma unroll
        for (int kk = 0; kk < 2; ++kk) {
            short8 af[4], bv[4];
            #pragma unroll
            for (int i = 0; i < 4; ++i)
                af[i] = *(const short8*)&sAs[(wm * 64 + i * 16 + fr) * 64 + (((kk << 2) + fq) ^ (fr & 7)) * 8];
            #pragma unroll
            for (int j = 0; j < 4; ++j)
                bv[j] = *(const short8*)&sBs[(wn * 64 + j * 16 + fr) * 64 + (((kk << 2) + fq) ^ (fr & 7)) * 8];
            #pragma unroll
            for (int i = 0; i < 4; ++i)
                #pragma unroll
                for (int j = 0; j < 4; ++j)
                    acc[i][j] = __builtin_amdgcn_mfma_f32_16x16x32_bf16(af[i], bv[j], acc[i][j], 0, 0, 0);
        }
        __builtin_amdgcn_s_barrier();   // protects next PACKST overwrite
    }
#undef GLOADF
#undef PACKST

    // ---- epilogue: transposed bf16 tile via LDS + LN partials ----
    unsigned short* sc = sh;                       // [128][136] = 34816 B
    float2* red = (float2*)(sh + 17408);           // [128][8] = 8192 B
    const int bB   = bm >> 9;
    const int tok0 = bm & 511;
    const int chunk = (bm >> 7) & 3;
    #pragma unroll
    for (int j = 0; j < 4; ++j) {
        const int col = wn * 64 + j * 16 + fr;
        const float bj = in_b[bn + col];
        float s = 0.f, q = 0.f;
        #pragma unroll
        for (int i = 0; i < 4; ++i) {
            const int row0 = wm * 64 + i * 16 + fq * 4;
            #pragma unroll
            for (int r = 0; r < 4; r += 2) {
                float v0 = acc[i][j][r] + bj;
                float v1 = acc[i][j][r + 1] + bj;
                s += v0 + v1;
                q = fmaf(v0, v0, fmaf(v1, v1, q));
                unsigned int pk = (unsigned int)f2b(v0) | ((unsigned int)f2b(v1) << 16);
                *(unsigned int*)&sc[col * 136 + row0 + r] = pk;
            }
        }
        red[col * 8 + wm * 4 + fq] = make_float2(s, q);
    }
    __syncthreads();
    if (t < 128) {
        float S = 0.f, Q = 0.f;
        #pragma unroll
        for (int k = 0; k < 8; ++k) { float2 v = red[t * 8 + k]; S += v.x; Q += v.y; }
        part[((size_t)bB * Dv + bn + t) * 4 + chunk] = make_float2(S, Q);
    }
    #pragma unroll
    for (int k = 0; k < 8; ++k) {
        const int c = t + k * 256;
        const int dl = c >> 4, tk = c & 15;
        uint4 v = *(const uint4*)&sc[dl * 136 + tk * 8];
        *(uint4*)&xpT[((size_t)bB * Dv + bn + dl) * Nv + tok0 + tk * 8] = v;
    }
}

// ---------------- mixer GEMM: in-block router + blend-in-staging + LN-fold --
// Using sum_n(softmax row)=1:  sum_n xn[d,n]*wa[m,n] = rstd_d*(sum_n xp[d,n]*wa[m,n] - mu_d)
__global__ __launch_bounds__(256) void k_mixg(
    const unsigned short* __restrict__ wa,    // [E*H][512][512] bf16 (softmaxed)
    const unsigned short* __restrict__ xpT,   // [8][1024][512] bf16 (raw xp, transposed)
    const float* __restrict__ bias,           // [E][H][512] f32
    const float* __restrict__ xmean,          // [8][1024] f32 RAW col sums
    const float* __restrict__ router_w,       // [E][1024] f32
    const float2* __restrict__ part,          // [(b*Dv+d)*4 + chunk] (sum,sumsq)
    unsigned short* __restrict__ y,           // [8][512][1024] bf16
    float* __restrict__ aux_out) {
    __shared__ __align__(16) unsigned short sA[2][128 * 64];
    __shared__ __align__(16) unsigned short sB[2][128 * 64];
    __shared__ float probs[Bv][Ev];
    __shared__ float twsh[Bv][2];
    __shared__ int   tsel[Bv][2];
    __shared__ int   top1s[Bv];
    const int t = threadIdx.x;
    const int bm = blockIdx.x * 128;  // m tile (4)
    const int bh = blockIdx.y;        // 64
    const int b = bh >> 3, h = bh & 7;

    {
        int pid = t >> 2, l = t & 3;
        int rb = pid >> 3, re = pid & 7;
        const float4* xm = (const float4*)(xmean + rb * Dv);
        const float4* rw = (const float4*)(router_w + re * Dv);
        float s = 0.f;
        #pragma unroll
        for (int j = 0; j < 64; ++j) {
            float4 aa = xm[l + j * 4], ww = rw[l + j * 4];
            s = fmaf(aa.x, ww.x, s); s = fmaf(aa.y, ww.y, s);
            s = fmaf(aa.z, ww.z, s); s = fmaf(aa.w, ww.w, s);
        }
        s += __shfl_xor(s, 1); s += __shfl_xor(s, 2);
        if (l == 0) probs[rb][re] = s * (1.f / Nv);   // raw sums -> mean
    }
    __syncthreads();
    if (t < Bv) {
        int bb = t;
        float mx = -1e30f;
        for (int e2 = 0; e2 < Ev; ++e2) mx = fmaxf(mx, probs[bb][e2]);
        float sum = 0.f;
        for (int e2 = 0; e2 < Ev; ++e2) { float v = __expf(probs[bb][e2] - mx); probs[bb][e2] = v; sum += v; }
        float inv = 1.f / sum;
        for (int e2 = 0; e2 < Ev; ++e2) probs[bb][e2] *= inv;
        int i0 = 0; float p0 = probs[bb][0];
        for (int e2 = 1; e2 < Ev; ++e2) if (probs[bb][e2] > p0) { p0 = probs[bb][e2]; i0 = e2; }
        int i1 = -1; float p1 = -1.f;
        for (int e2 = 0; e2 < Ev; ++e2) if (e2 != i0 && probs[bb][e2] > p1) { p1 = probs[bb][e2]; i1 = e2; }
        float s2 = p0 + p1;
        tsel[bb][0] = i0; tsel[bb][1] = i1;
        twsh[bb][0] = p0 / s2; twsh[bb][1] = p1 / s2;
        top1s[bb] = i0;
    }
    __syncthreads();
    if (blockIdx.x == 0 && bh == 0 && t == 0) {
        float aux = 0.f;
        for (int e2 = 0; e2 < Ev; ++e2) {
            float pm = 0.f, mm = 0.f;
            for (int bb = 0; bb < Bv; ++bb) { pm += probs[bb][e2]; mm += (top1s[bb] == e2) ? 1.f : 0.f; }
            aux += (pm / Bv) * (mm / Bv);
        }
        *aux_out = aux * Ev;
    }
    const int e0 = tsel[b][0], e1 = tsel[b][1];
    const float tw0 = twsh[b][0], tw1 = twsh[b][1];

    const int lane = t & 63;
    const int w = t >> 6, wm = w >> 1, wn = w & 1;
    const int fr = lane & 15, fq = lane >> 4;

    float rstd_j[4], nmr_j[4];
    #pragma unroll
    for (int j = 0; j < 4; ++j) {
        const int dg = h * HDv + wn * 64 + j * 16 + fr;
        const float2* pp = part + ((size_t)b * Dv + dg) * 4;
        float S = 0.f, Q = 0.f;
        #pragma unroll
        for (int cc = 0; cc < 4; ++cc) { float2 v = pp[cc]; S += v.x; Q += v.y; }
        float mu = S * (1.f / Nv);
        float var = Q * (1.f / Nv) - mu * mu;
        float rs = rsqrtf(var + EPSv);
        rstd_j[j] = rs; nmr_j[j] = -mu * rs;
    }

    const unsigned short* A0 = wa + (size_t)(e0 * Hv + h) * Nv * Nv;
    const unsigned short* A1 = wa + (size_t)(e1 * Hv + h) * Nv * Nv;
    const unsigned short* Bb = xpT + ((size_t)b * Dv + h * HDv) * Nv;
    const int NT = Nv >> 6;  // 8
    f32x4 acc[4][4] = {};
    uint4 ra0[4], ra1[4];

#define BSTAGE(s, k0)                                                       \
    {                                                                       \
        _Pragma("unroll")                                                   \
        for (int i_ = 0; i_ < 4; ++i_) {                                    \
            int c_ = t + i_ * 256;                                          \
            int row_ = c_ >> 3, col_ = c_ & 7;                              \
            int cs_ = col_ ^ (row_ & 7);                                    \
            gld16(Bb + (size_t)row_ * Nv + (k0) + cs_ * 8, &sB[s][c_ * 8]); \
        }                                                                   \
    }
#define ALOAD(k0)                                                           \
    {                                                                       \
        _Pragma("unroll")                                                   \
        for (int i_ = 0; i_ < 4; ++i_) {                                    \
            int c_ = t + i_ * 256;                                          \
            int row_ = c_ >> 3, col_ = c_ & 7;                              \
            int cs_ = col_ ^ (row_ & 7);                                    \
            size_t off_ = (size_t)(bm + row_) * Nv + (k0) + cs_ * 8;        \
            ra0[i_] = *(const uint4*)&A0[off_];                             \
            ra1[i_] = *(const uint4*)&A1[off_];                             \
        }                                                                   \
    }

    BSTAGE(0, 0);
    ALOAD(0);
    for (int it = 0; it < NT; ++it) {
        if (it + 1 < NT) {
            BSTAGE((it + 1) & 1, (it + 1) * 64);
            asm volatile("s_waitcnt vmcnt(4)" ::: "memory");
        } else {
            asm volatile("s_waitcnt vmcnt(0)" ::: "memory");
        }
        #pragma unroll
        for (int i = 0; i < 4; ++i) {
            int c = t + i * 256;
            uint4 o;
            o.x = blend2(ra0[i].x, ra1[i].x, tw0, tw1);
            o.y = blend2(ra0[i].y, ra1[i].y, tw0, tw1);
            o.z = blend2(ra0[i].z, ra1[i].z, tw0, tw1);
            o.w = blend2(ra0[i].w, ra1[i].w, tw0, tw1);
            *(uint4*)&sA[it & 1][c * 8] = o;
        }
        if (it + 1 < NT) ALOAD((it + 1) * 64);
        asm volatile("s_waitcnt lgkmcnt(0)" ::: "memory");
        __builtin_amdgcn_s_barrier();
        const unsigned short* pA = sA[it & 1];
        const unsigned short* pB = sB[it & 1];
        #pragma unroll
        for (int kk = 0; kk < 2; ++kk) {
            short8 af[4], bv[4];
            #pragma unroll
            for (int i = 0; i < 4; ++i)
                af[i] = *(const short8*)&pA[(wm * 64 + i * 16 + fr) * 64 + (((kk << 2) + fq) ^ (fr & 7)) * 8];
            #pragma unroll
            for (int j = 0; j < 4; ++j)
                bv[j] = *(const short8*)&pB[(wn * 64 + j * 16 + fr) * 64 + (((kk << 2) + fq) ^ (fr & 7)) * 8];
            #pragma unroll
            for (int i = 0; i < 4; ++i)
                #pragma unroll
                for (int j = 0; j < 4; ++j)
                    acc[i][j] = __builtin_amdgcn_mfma_f32_16x16x32_bf16(af[i], bv[j], acc[i][j], 0, 0, 0);
        }
        __builtin_amdgcn_s_barrier();
    }
#undef BSTAGE
#undef ALOAD
    #pragma unroll
    for (int i = 0; i < 4; ++i) {
        #pragma unroll
        for (int r = 0; r < 4; ++r) {
            const int m = bm + wm * 64 + i * 16 + fq * 4 + r;
            const float br = tw0 * bias[(size_t)(e0 * Hv + h) * Nv + m]
                           + tw1 * bias[(size_t)(e1 * Hv + h) * Nv + m];
            #pragma unroll
            for (int j = 0; j < 4; ++j) {
                const int d = wn * 64 + j * 16 + fr;
                float v = fmaf(acc[i][j][r], rstd_j[j], nmr_j[j] + br);
                y[((size_t)b * Nv + m) * Dv + h * HDv + d] = f2b(v);
            }
        }
    }
}

// ---------------- final GEMM (3-buffer depth-2), f32 out --------------------
__global__ __launch_bounds__(256) void k_gemm0(
    const unsigned short* __restrict__ A,   // [4096][1024] bf16
    const unsigned short* __restrict__ W,   // [1024][1024] bf16
    const float* __restrict__ bias,
    float* __restrict__ C) {
    __shared__ __align__(16) unsigned short sA[3][128 * 64];
    __shared__ __align__(16) unsigned short sB[3][128 * 64];
    const int t = threadIdx.x;
    const int bn = blockIdx.x * 128;
    const int bm = blockIdx.y * 128;
    const int lane = t & 63;
    const int w = t >> 6, wm = w >> 1, wn = w & 1;
    const int fr = lane & 15, fq = lane >> 4;
    const int K = Dv, NT = 16, Nn = Dv;
    f32x4 acc[4][4] = {};

#define STAGE(s, k0)                                                        \
    {                                                                       \
        _Pragma("unroll")                                                   \
        for (int i_ = 0; i_ < 4; ++i_) {                                    \
            int c_ = t + i_ * 256;                                          \
            int row_ = c_ >> 3, col_ = c_ & 7;                              \
            int cs_ = col_ ^ (row_ & 7);                                    \
            gld16(A + (size_t)(bm + row_) * K + (k0) + cs_ * 8, &sA[s][c_ * 8]); \
            gld16(W + (size_t)(bn + row_) * K + (k0) + cs_ * 8, &sB[s][c_ * 8]); \
        }                                                                   \
    }

    STAGE(0, 0);
    STAGE(1, 64);
    for (int it = 0; it < NT; ++it) {
        if (it + 2 < NT) {
            STAGE((it + 2) % 3, (it + 2) * 64);
            asm volatile("s_waitcnt vmcnt(16)" ::: "memory");
        } else if (it + 1 < NT) {
            asm volatile("s_waitcnt vmcnt(8)" ::: "memory");
        } else {
            asm volatile("s_waitcnt vmcnt(0)" ::: "memory");
        }
        __builtin_amdgcn_s_barrier();
        const unsigned short* pA = sA[it % 3];
        const unsigned short* pB = sB[it % 3];
        #pragma unroll
        for (int kk = 0; kk < 2; ++kk) {
            short8 af[4], bv[4];
            #pragma unroll
            for (int i = 0; i < 4; ++i)
                af[i] = *(const short8*)&pA[(wm * 64 + i * 16 + fr) * 64 + (((kk << 2) + fq) ^ (fr & 7)) * 8];
            #pragma unroll
            for (int j = 0; j < 4; ++j)
                bv[j] = *(const short8*)&pB[(wn * 64 + j * 16 + fr) * 64 + (((kk << 2) + fq) ^ (fr & 7)) * 8];
            #pragma unroll
            for (int i = 0; i < 4; ++i)
                #pragma unroll
                for (int j = 0; j < 4; ++j)
                    acc[i][j] = __builtin_amdgcn_mfma_f32_16x16x32_bf16(af[i], bv[j], acc[i][j], 0, 0, 0);
        }
        __builtin_amdgcn_s_barrier();
    }
#undef STAGE
    #pragma unroll
    for (int j = 0; j < 4; ++j) {
        const int n = bn + wn * 64 + j * 16 + fr;
        const float bj = bias[n];
        #pragma unroll
        for (int i = 0; i < 4; ++i) {
            const int m0 = bm + wm * 64 + i * 16 + fq * 4;
            #pragma unroll
            for (int r = 0; r < 4; ++r)
                C[(size_t)(m0 + r) * Nn + n] = acc[i][j][r] + bj;
        }
    }
}

extern "C" void kernel_launch(void* const* d_in, const int* in_sizes, int n_in,
                              void* d_out, int out_size, void* d_ws, size_t ws_size,
                              hipStream_t stream) {
    const float* x        = (const float*)d_in[0];
    const float* weight   = (const float*)d_in[1];
    const float* bias     = (const float*)d_in[2];
    const float* router_w = (const float*)d_in[3];
    const float* in_w     = (const float*)d_in[4];
    const float* in_b     = (const float*)d_in[5];
    const float* out_w    = (const float*)d_in[6];
    const float* out_b    = (const float*)d_in[7];
    float* out = (float*)d_out;

    if (ws_size < ((size_t)63 << 20)) return;

    char* wsb = (char*)d_ws;
    float*  xmean  = (float*)(wsb);                                  // 32 KB
    float2* part   = (float2*)(wsb + (64 << 10));                    // 256 KB
    unsigned short* out_wb = (unsigned short*)(wsb + ((size_t)4 << 20));   // 2 MB
    unsigned short* y      = (unsigned short*)(wsb + ((size_t)8 << 20));   // 8 MB
    unsigned short* xpT    = (unsigned short*)(wsb + ((size_t)16 << 20));  // 8 MB
    unsigned short* wa     = (unsigned short*)(wsb + ((size_t)24 << 20));  // 32 MB

    hipMemsetAsync(xmean, 0, (size_t)Bv * Dv * sizeof(float), stream);
    k_fused1<<<1536, 256, 0, stream>>>(x, in_w, weight, out_w, in_b,
                                       xpT, part, xmean, wa, out_wb);
    k_mixg<<<dim3(4, 64), 256, 0, stream>>>(wa, xpT, bias, xmean, router_w, part, y,
                                            out + (size_t)Bv * Nv * Dv);
    k_gemm0<<<dim3(8, 32), 256, 0, stream>>>(y, out_wb, out_b, out);
}

// Round 12
// 80.913 us; speedup vs baseline: 1.0302x; 1.0302x over previous
//
#include <hip/hip_runtime.h>
#include <hip/hip_bf16.h>

#define Bv 8
#define Nv 512
#define Dv 1024
#define Ev 8
#define Hv 8
#define HDv 128
#define EPSv 1e-5f

typedef __attribute__((ext_vector_type(8))) short short8;
typedef __attribute__((ext_vector_type(4))) float f32x4;

__device__ __forceinline__ unsigned short f2b(float f) {
    __hip_bfloat16 h = __float2bfloat16(f);
    return *reinterpret_cast<unsigned short*>(&h);
}
__device__ __forceinline__ float bf2f(unsigned int u) {
    union { unsigned int i; float f; } v; v.i = u << 16; return v.f;
}

// async global->LDS, 16 bytes per lane; LDS dest must be linear (base + lane*16)
__device__ __forceinline__ void gld16(const void* g, void* l) {
    __builtin_amdgcn_global_load_lds(
        (const __attribute__((address_space(1))) void*)(uintptr_t)(g),
        (__attribute__((address_space(3))) void*)(uintptr_t)(l), 16, 0, 0);
}

// ---------------- preprocessing: only the small casts -----------------------
//   blocks [0,128):    cast x->bf16 + column partial sums
//   blocks [128,256):  cast in_w -> bf16
//   blocks [256,384):  cast out_w -> bf16
__global__ __launch_bounds__(256) void k_preA(const float* __restrict__ x,
                                              const float* __restrict__ w1,
                                              const float* __restrict__ w2,
                                              unsigned short* __restrict__ xb,
                                              float* __restrict__ part_x,
                                              unsigned short* __restrict__ w1b,
                                              unsigned short* __restrict__ w2b) {
    int bid = blockIdx.x;
    int t = threadIdx.x;
    if (bid < 128) {
        int b = bid >> 4, c = bid & 15;
        const float* px = x + ((size_t)b * Nv + c * 32) * Dv + t * 4;
        unsigned short* qx = xb + ((size_t)b * Nv + c * 32) * Dv + t * 4;
        float4 s4 = make_float4(0.f, 0.f, 0.f, 0.f);
        #pragma unroll 8
        for (int r = 0; r < 32; ++r) {
            float4 v = *(const float4*)(px + (size_t)r * Dv);
            s4.x += v.x; s4.y += v.y; s4.z += v.z; s4.w += v.w;
            uint2 pk;
            pk.x = (unsigned)f2b(v.x) | ((unsigned)f2b(v.y) << 16);
            pk.y = (unsigned)f2b(v.z) | ((unsigned)f2b(v.w) << 16);
            *(uint2*)(qx + (size_t)r * Dv) = pk;
        }
        *(float4*)(part_x + ((size_t)(b * 16 + c)) * Dv + t * 4) = s4;
        return;
    }
    const float* src; unsigned short* dst; int base;
    if (bid < 256) { src = w1; dst = w1b; base = (bid - 128) * 8192; }
    else           { src = w2; dst = w2b; base = (bid - 256) * 8192; }
    #pragma unroll
    for (int i = 0; i < 8; ++i) {
        float4 a = *(const float4*)(src + base + i * 1024 + t * 4);
        uint2 p;
        p.x = (unsigned)f2b(a.x) | ((unsigned)f2b(a.y) << 16);
        p.y = (unsigned)f2b(a.z) | ((unsigned)f2b(a.w) << 16);
        *(uint2*)(dst + base + i * 1024 + t * 4) = p;
    }
}

// ---------------- bf16 MFMA GEMM, depth-2 pipelined (3 LDS buffers) ---------
// MODE 0: C[m,n] = A[m,:].W[n,:] + bias[n], f32 out, normal layout
// MODE 2: bf16 out TRANSPOSED to Cv[b][n(d)][tok] (shape [Bv][Dv][Nv]) plus
//         per-(b,d) partial LN sums part[(b*Dv+d)*4 + m_chunk] = (sum, sumsq);
//         also reduces part_x -> xmean (overlapped with staging prologue)
template <int MODE>
__global__ __launch_bounds__(256) void k_gemm(
    const unsigned short* __restrict__ A,   // [M][K] bf16
    const unsigned short* __restrict__ W,   // [Nn][K] bf16
    const float* __restrict__ bias,         // [Nn] f32
    void* __restrict__ Cv,
    float2* __restrict__ part,
    const float* __restrict__ part_x,
    float* __restrict__ xmean,
    int M, int Nn, int K) {
    __shared__ __align__(16) unsigned short sA[3][128 * 64];
    __shared__ __align__(16) unsigned short sB[3][128 * 64];
    const int t = threadIdx.x;
    const int bn = blockIdx.x * 128;
    const int bm = blockIdx.y * 128;
    const int lane = t & 63;
    const int w = t >> 6, wm = w >> 1, wn = w & 1;
    const int fr = lane & 15, fq = lane >> 4;
    const int NT = K >> 6;
    f32x4 acc[4][4] = {};

#define STAGE(s, k0)                                                        \
    {                                                                       \
        _Pragma("unroll")                                                   \
        for (int i_ = 0; i_ < 4; ++i_) {                                    \
            int c_ = t + i_ * 256;                                          \
            int row_ = c_ >> 3, col_ = c_ & 7;                              \
            int cs_ = col_ ^ (row_ & 7);                                    \
            gld16(A + (size_t)(bm + row_) * K + (k0) + cs_ * 8, &sA[s][c_ * 8]); \
            gld16(W + (size_t)(bn + row_) * K + (k0) + cs_ * 8, &sB[s][c_ * 8]); \
        }                                                                   \
    }

    STAGE(0, 0);
    STAGE(1, 64);
    if (MODE == 2) {
        // xmean reduce: 256 blocks x 32 outputs, overlapped with async staging
        int blk = blockIdx.y * 8 + blockIdx.x;      // 0..255
        int o = blk * 32 + (t >> 3);                // output idx over 8192
        int c2 = t & 7;
        int b2 = o >> 10, d2 = o & 1023;
        float S = part_x[((size_t)(b2 * 16 + c2)) * Dv + d2]
                + part_x[((size_t)(b2 * 16 + c2 + 8)) * Dv + d2];
        S += __shfl_xor(S, 1); S += __shfl_xor(S, 2); S += __shfl_xor(S, 4);
        if (c2 == 0) xmean[o] = S * (1.f / Nv);
    }
    for (int it = 0; it < NT; ++it) {
        if (it + 2 < NT) {
            STAGE((it + 2) % 3, (it + 2) * 64);
            asm volatile("s_waitcnt vmcnt(16)" ::: "memory");
        } else if (it + 1 < NT) {
            asm volatile("s_waitcnt vmcnt(8)" ::: "memory");
        } else {
            asm volatile("s_waitcnt vmcnt(0)" ::: "memory");
        }
        __builtin_amdgcn_s_barrier();
        const unsigned short* pA = sA[it % 3];
        const unsigned short* pB = sB[it % 3];
        #pragma unroll
        for (int kk = 0; kk < 2; ++kk) {
            short8 af[4], bv[4];
            #pragma unroll
            for (int i = 0; i < 4; ++i)
                af[i] = *(const short8*)&pA[(wm * 64 + i * 16 + fr) * 64 + (((kk << 2) + fq) ^ (fr & 7)) * 8];
            #pragma unroll
            for (int j = 0; j < 4; ++j)
                bv[j] = *(const short8*)&pB[(wn * 64 + j * 16 + fr) * 64 + (((kk << 2) + fq) ^ (fr & 7)) * 8];
            #pragma unroll
            for (int i = 0; i < 4; ++i)
                #pragma unroll
                for (int j = 0; j < 4; ++j)
                    acc[i][j] = __builtin_amdgcn_mfma_f32_16x16x32_bf16(af[i], bv[j], acc[i][j], 0, 0, 0);
        }
        __builtin_amdgcn_s_barrier();
    }
#undef STAGE
    if (MODE == 0) {
        #pragma unroll
        for (int j = 0; j < 4; ++j) {
            const int n = bn + wn * 64 + j * 16 + fr;
            const float bj = bias[n];
            #pragma unroll
            for (int i = 0; i < 4; ++i) {
                const int m0 = bm + wm * 64 + i * 16 + fq * 4;
                #pragma unroll
                for (int r = 0; r < 4; ++r)
                    ((float*)Cv)[(size_t)(m0 + r) * Nn + n] = acc[i][j][r] + bj;
            }
        }
    } else {
        // ---- transposed bf16 tile via LDS (K-loop LDS is dead now) + stats ----
        unsigned short* sc = &sA[0][0];        // [128 d][136 tok] ushort = 34 KB
        float2* red = (float2*)&sB[0][0];      // [128 d][8] partial (s,q) = 8 KB
        const int bB   = bm >> 9;              // batch
        const int tok0 = bm & 511;             // token offset within batch
        const int chunk = (bm >> 7) & 3;       // which 128-token chunk
        #pragma unroll
        for (int j = 0; j < 4; ++j) {
            const int col = wn * 64 + j * 16 + fr;       // local d
            const float bj = bias[bn + col];
            float s = 0.f, q = 0.f;
            #pragma unroll
            for (int i = 0; i < 4; ++i) {
                const int row0 = wm * 64 + i * 16 + fq * 4;  // local token
                #pragma unroll
                for (int r = 0; r < 4; r += 2) {
                    float v0 = acc[i][j][r] + bj;
                    float v1 = acc[i][j][r + 1] + bj;
                    s += v0 + v1;
                    q = fmaf(v0, v0, fmaf(v1, v1, q));
                    unsigned int pk = (unsigned int)f2b(v0) | ((unsigned int)f2b(v1) << 16);
                    *(unsigned int*)&sc[col * 136 + row0 + r] = pk;
                }
            }
            red[col * 8 + wm * 4 + fq] = make_float2(s, q);
        }
        __syncthreads();
        if (t < 128) {
            float S = 0.f, Q = 0.f;
            #pragma unroll
            for (int k = 0; k < 8; ++k) { float2 v = red[t * 8 + k]; S += v.x; Q += v.y; }
            part[((size_t)bB * Dv + bn + t) * 4 + chunk] = make_float2(S, Q);
        }
        unsigned short* dst = (unsigned short*)Cv;
        #pragma unroll
        for (int k = 0; k < 8; ++k) {
            const int c = t + k * 256;
            const int dl = c >> 4, tk = c & 15;
            uint4 v = *(const uint4*)&sc[dl * 136 + tk * 8];
            *(uint4*)&dst[((size_t)bB * Dv + bn + dl) * Nv + tok0 + tk * 8] = v;
        }
    }
}

// ---------------- mixer GEMM: two-expert unnormalized-exp accumulation -----
// 512 threads (8 waves), BM=128, single-read of raw f32 weight, two acc sets.
//   acc_e[m,d] = sum_n exp(w_e[m,n]) * xp[d,n];  s_e[m] = sum_n exp(w_e[m,n])
//   out = rstd_d*((tw0/s0[m])*acc0 + (tw1/s1[m])*acc1 - mu_d) + blended bias
// No max-subtraction: |w| <= 1/sqrt(512) so exp in [0.957, 1.045].
// Per-wave tile 32m x 64d; per-thread: 2 A-chunks (x2 experts), 2 B gld16.
// vmcnt: steady queue [ALOAD(it)8 + BSTAGE(it)2 + ALOAD(it+1)8 + BSTAGE(it+1)2]
//        = 20 at the wait -> vmcnt(10) drains ALOAD(it)+BSTAGE(it); 0 at last.
__global__ __launch_bounds__(512) void k_mixg(
    const float* __restrict__ weight,         // [E][H][512][512] f32 raw
    const unsigned short* __restrict__ xpT,   // [8][1024][512] bf16 (raw xp, transposed)
    const float* __restrict__ bias,           // [E][H][512] f32
    const float* __restrict__ xmean,          // [8][1024] f32
    const float* __restrict__ router_w,       // [E][1024] f32
    const float2* __restrict__ part,          // [(b*Dv+d)*4 + chunk] (sum,sumsq)
    unsigned short* __restrict__ y,           // [8][512][1024] bf16
    float* __restrict__ aux_out) {
    __shared__ __align__(16) unsigned short sA0[128 * 64];   // 16 KB
    __shared__ __align__(16) unsigned short sA1[128 * 64];   // 16 KB
    __shared__ __align__(16) unsigned short sB[2][128 * 64]; // 32 KB
    __shared__ float rowc0[128], rowc1[128];
    __shared__ float probs[Bv][Ev];
    __shared__ float twsh[Bv][2];
    __shared__ int   tsel[Bv][2];
    __shared__ int   top1s[Bv];
    const int t = threadIdx.x;
    const int bm = blockIdx.x * 128;  // m tile (4)
    const int bh = blockIdx.y;        // 64
    const int b = bh >> 3, h = bh & 7;

    // ---- redundant per-block router (threads [0,256)): 64 dots x 4 lanes ----
    if (t < 256) {
        int pid = t >> 2, l = t & 3;
        int rb = pid >> 3, re = pid & 7;
        const float4* xm = (const float4*)(xmean + rb * Dv);
        const float4* rw = (const float4*)(router_w + re * Dv);
        float s = 0.f;
        #pragma unroll
        for (int j = 0; j < 64; ++j) {
            float4 aa = xm[l + j * 4], ww = rw[l + j * 4];
            s = fmaf(aa.x, ww.x, s); s = fmaf(aa.y, ww.y, s);
            s = fmaf(aa.z, ww.z, s); s = fmaf(aa.w, ww.w, s);
        }
        s += __shfl_xor(s, 1); s += __shfl_xor(s, 2);
        if (l == 0) probs[rb][re] = s;
    }
    __syncthreads();
    if (t < Bv) {
        int bb = t;
        float mx = -1e30f;
        for (int e2 = 0; e2 < Ev; ++e2) mx = fmaxf(mx, probs[bb][e2]);
        float sum = 0.f;
        for (int e2 = 0; e2 < Ev; ++e2) { float v = __expf(probs[bb][e2] - mx); probs[bb][e2] = v; sum += v; }
        float inv = 1.f / sum;
        for (int e2 = 0; e2 < Ev; ++e2) probs[bb][e2] *= inv;
        int i0 = 0; float p0 = probs[bb][0];
        for (int e2 = 1; e2 < Ev; ++e2) if (probs[bb][e2] > p0) { p0 = probs[bb][e2]; i0 = e2; }
        int i1 = -1; float p1 = -1.f;
        for (int e2 = 0; e2 < Ev; ++e2) if (e2 != i0 && probs[bb][e2] > p1) { p1 = probs[bb][e2]; i1 = e2; }
        float s2 = p0 + p1;
        tsel[bb][0] = i0; tsel[bb][1] = i1;
        twsh[bb][0] = p0 / s2; twsh[bb][1] = p1 / s2;
        top1s[bb] = i0;
    }
    __syncthreads();
    if (blockIdx.x == 0 && bh == 0 && t == 0) {
        float aux = 0.f;
        for (int e2 = 0; e2 < Ev; ++e2) {
            float pm = 0.f, mm = 0.f;
            for (int bb = 0; bb < Bv; ++bb) { pm += probs[bb][e2]; mm += (top1s[bb] == e2) ? 1.f : 0.f; }
            aux += (pm / Bv) * (mm / Bv);
        }
        *aux_out = aux * Ev;
    }
    const int e0 = tsel[b][0], e1 = tsel[b][1];
    const float tw0 = twsh[b][0], tw1 = twsh[b][1];

    const int lane = t & 63;
    const int w = t >> 6, wm = w >> 1, wn = w & 1;   // wm 0..3, wn 0..1
    const int fr = lane & 15, fq = lane >> 4;

    // ---- LN stats from gemm1 partials ----
    float rstd_j[4], nmr_j[4];
    #pragma unroll
    for (int j = 0; j < 4; ++j) {
        const int dg = h * HDv + wn * 64 + j * 16 + fr;
        const float2* pp = part + ((size_t)b * Dv + dg) * 4;
        float S = 0.f, Q = 0.f;
        #pragma unroll
        for (int cc = 0; cc < 4; ++cc) { float2 v = pp[cc]; S += v.x; Q += v.y; }
        float mu = S * (1.f / Nv);
        float var = Q * (1.f / Nv) - mu * mu;
        float rs = rsqrtf(var + EPSv);
        rstd_j[j] = rs; nmr_j[j] = -mu * rs;
    }

    const float* W0 = weight + (size_t)(e0 * Hv + h) * Nv * Nv;
    const float* W1 = weight + (size_t)(e1 * Hv + h) * Nv * Nv;
    const unsigned short* Bb = xpT + ((size_t)b * Dv + h * HDv) * Nv;

    f32x4 acc0[2][4] = {}, acc1[2][4] = {};
    float4 raA0[2][2], raA1[2][2], raB0[2][2], raB1[2][2];
    float s0p[2] = {0.f, 0.f}, s1p[2] = {0.f, 0.f};

#define BSTAGE(s, k0)                                                       \
    {                                                                       \
        _Pragma("unroll")                                                   \
        for (int i_ = 0; i_ < 2; ++i_) {                                    \
            int c_ = t + i_ * 512;                                          \
            int row_ = c_ >> 3, col_ = c_ & 7;                              \
            int cs_ = col_ ^ (row_ & 7);                                    \
            gld16(Bb + (size_t)row_ * Nv + (k0) + cs_ * 8, &sB[s][c_ * 8]); \
        }                                                                   \
    }
#define ALOADG(RA0, RA1, k0)                                                \
    {                                                                       \
        _Pragma("unroll")                                                   \
        for (int i_ = 0; i_ < 2; ++i_) {                                    \
            int c_ = t + i_ * 512;                                          \
            int row_ = c_ >> 3, col_ = c_ & 7;                              \
            int cs_ = col_ ^ (row_ & 7);                                    \
            size_t off_ = (size_t)(bm + row_) * Nv + (k0) + cs_ * 8;        \
            RA0[i_][0] = *(const float4*)&W0[off_];                         \
            RA0[i_][1] = *(const float4*)&W0[off_ + 4];                     \
            RA1[i_][0] = *(const float4*)&W1[off_];                         \
            RA1[i_][1] = *(const float4*)&W1[off_ + 4];                     \
        }                                                                   \
    }
#define BLEND(RA0, RA1)                                                     \
    {                                                                       \
        _Pragma("unroll")                                                   \
        for (int i_ = 0; i_ < 2; ++i_) {                                    \
            int c_ = t + i_ * 512;                                          \
            float e0v[8], e1v[8];                                           \
            const float4 a0_ = RA0[i_][0], a1_ = RA0[i_][1];                \
            const float4 b0_ = RA1[i_][0], b1_ = RA1[i_][1];                \
            e0v[0] = __expf(a0_.x); e0v[1] = __expf(a0_.y);                 \
            e0v[2] = __expf(a0_.z); e0v[3] = __expf(a0_.w);                 \
            e0v[4] = __expf(a1_.x); e0v[5] = __expf(a1_.y);                 \
            e0v[6] = __expf(a1_.z); e0v[7] = __expf(a1_.w);                 \
            e1v[0] = __expf(b0_.x); e1v[1] = __expf(b0_.y);                 \
            e1v[2] = __expf(b0_.z); e1v[3] = __expf(b0_.w);                 \
            e1v[4] = __expf(b1_.x); e1v[5] = __expf(b1_.y);                 \
            e1v[6] = __expf(b1_.z); e1v[7] = __expf(b1_.w);                 \
            s0p[i_] += ((e0v[0] + e0v[1]) + (e0v[2] + e0v[3]))              \
                     + ((e0v[4] + e0v[5]) + (e0v[6] + e0v[7]));             \
            s1p[i_] += ((e1v[0] + e1v[1]) + (e1v[2] + e1v[3]))              \
                     + ((e1v[4] + e1v[5]) + (e1v[6] + e1v[7]));             \
            uint4 p0_, p1_;                                                 \
            p0_.x = (unsigned)f2b(e0v[0]) | ((unsigned)f2b(e0v[1]) << 16);  \
            p0_.y = (unsigned)f2b(e0v[2]) | ((unsigned)f2b(e0v[3]) << 16);  \
            p0_.z = (unsigned)f2b(e0v[4]) | ((unsigned)f2b(e0v[5]) << 16);  \
            p0_.w = (unsigned)f2b(e0v[6]) | ((unsigned)f2b(e0v[7]) << 16);  \
            p1_.x = (unsigned)f2b(e1v[0]) | ((unsigned)f2b(e1v[1]) << 16);  \
            p1_.y = (unsigned)f2b(e1v[2]) | ((unsigned)f2b(e1v[3]) << 16);  \
            p1_.z = (unsigned)f2b(e1v[4]) | ((unsigned)f2b(e1v[5]) << 16);  \
            p1_.w = (unsigned)f2b(e1v[6]) | ((unsigned)f2b(e1v[7]) << 16);  \
            *(uint4*)&sA0[c_ * 8] = p0_;                                    \
            *(uint4*)&sA1[c_ * 8] = p1_;                                    \
        }                                                                   \
    }
#define MFMAPH(sbuf)                                                        \
    {                                                                       \
        const unsigned short* pB = sB[sbuf];                                \
        _Pragma("unroll")                                                   \
        for (int kk = 0; kk < 2; ++kk) {                                    \
            short8 bv[4];                                                   \
            _Pragma("unroll")                                               \
            for (int j = 0; j < 4; ++j)                                     \
                bv[j] = *(const short8*)&pB[(wn * 64 + j * 16 + fr) * 64 + (((kk << 2) + fq) ^ (fr & 7)) * 8]; \
            _Pragma("unroll")                                               \
            for (int i = 0; i < 2; ++i) {                                   \
                const int aoff = (wm * 32 + i * 16 + fr) * 64 + (((kk << 2) + fq) ^ (fr & 7)) * 8; \
                short8 af0 = *(const short8*)&sA0[aoff];                    \
                short8 af1 = *(const short8*)&sA1[aoff];                    \
                _Pragma("unroll")                                           \
                for (int j = 0; j < 4; ++j)                                 \
                    acc0[i][j] = __builtin_amdgcn_mfma_f32_16x16x32_bf16(af0, bv[j], acc0[i][j], 0, 0, 0); \
                _Pragma("unroll")                                           \
                for (int j = 0; j < 4; ++j)                                 \
                    acc1[i][j] = __builtin_amdgcn_mfma_f32_16x16x32_bf16(af1, bv[j], acc1[i][j], 0, 0, 0); \
            }                                                               \
        }                                                                   \
    }
#define FITER(it, RA0, RA1)                                                 \
    {                                                                       \
        if ((it) + 1 < 8) BSTAGE(((it) + 1) & 1, ((it) + 1) * 64);          \
        if ((it) < 7) { asm volatile("s_waitcnt vmcnt(10)" ::: "memory"); } \
        else          { asm volatile("s_waitcnt vmcnt(0)" ::: "memory"); }  \
        BLEND(RA0, RA1);                                                    \
        if ((it) + 2 < 8) ALOADG(RA0, RA1, ((it) + 2) * 64);                \
        asm volatile("s_waitcnt lgkmcnt(0)" ::: "memory");                  \
        __builtin_amdgcn_s_barrier();                                       \
        MFMAPH((it) & 1);                                                   \
        __builtin_amdgcn_s_barrier();                                       \
    }

    BSTAGE(0, 0);
    ALOADG(raA0, raA1, 0);
    ALOADG(raB0, raB1, 64);
    FITER(0, raA0, raA1);
    FITER(1, raB0, raB1);
    FITER(2, raA0, raA1);
    FITER(3, raB0, raB1);
    FITER(4, raA0, raA1);
    FITER(5, raB0, raB1);
    FITER(6, raA0, raA1);
    FITER(7, raB0, raB1);
#undef BSTAGE
#undef ALOADG
#undef BLEND
#undef MFMAPH
#undef FITER

    // ---- finalize row sums: reduce over the 8 lanes sharing each row ----
    #pragma unroll
    for (int i = 0; i < 2; ++i) {
        #pragma unroll
        for (int off = 1; off < 8; off <<= 1) {
            s0p[i] += __shfl_xor(s0p[i], off);
            s1p[i] += __shfl_xor(s1p[i], off);
        }
        int row = (t >> 3) + i * 64;   // == (t + i*512) >> 3
        if ((t & 7) == 0) {
            rowc0[row] = tw0 / s0p[i];
            rowc1[row] = tw1 / s1p[i];
        }
    }
    __syncthreads();

    // ---- epilogue: y = rstd_d*(c0*acc0 + c1*acc1 - mu_d) + blended bias ----
    #pragma unroll
    for (int i = 0; i < 2; ++i) {
        #pragma unroll
        for (int r = 0; r < 4; ++r) {
            const int ml = wm * 32 + i * 16 + fq * 4 + r;
            const int m = bm + ml;
            const float c0m = rowc0[ml], c1m = rowc1[ml];
            const float br = tw0 * bias[(size_t)(e0 * Hv + h) * Nv + m]
                           + tw1 * bias[(size_t)(e1 * Hv + h) * Nv + m];
            #pragma unroll
            for (int j = 0; j < 4; ++j) {
                const int d = wn * 64 + j * 16 + fr;
                float vb = c0m * acc0[i][j][r] + c1m * acc1[i][j][r];
                float v = fmaf(vb, rstd_j[j], nmr_j[j] + br);
                y[((size_t)b * Nv + m) * Dv + h * HDv + d] = f2b(v);
            }
        }
    }
}

extern "C" void kernel_launch(void* const* d_in, const int* in_sizes, int n_in,
                              void* d_out, int out_size, void* d_ws, size_t ws_size,
                              hipStream_t stream) {
    const float* x        = (const float*)d_in[0];
    const float* weight   = (const float*)d_in[1];
    const float* bias     = (const float*)d_in[2];
    const float* router_w = (const float*)d_in[3];
    const float* in_w     = (const float*)d_in[4];
    const float* in_b     = (const float*)d_in[5];
    const float* out_w    = (const float*)d_in[6];
    const float* out_b    = (const float*)d_in[7];
    float* out = (float*)d_out;

    if (ws_size < ((size_t)63 << 20)) return;

    char* wsb = (char*)d_ws;
    float*  xmean  = (float*)(wsb);                                  // 32 KB
    float2* part   = (float2*)(wsb + (64 << 10));                    // 256 KB
    float*  part_x = (float*)(wsb + (512 << 10));                    // 512 KB
    unsigned short* in_wb  = (unsigned short*)(wsb + ((size_t)2 << 20));   // 2 MB
    unsigned short* out_wb = (unsigned short*)(wsb + ((size_t)4 << 20));   // 2 MB
    unsigned short* xb     = (unsigned short*)(wsb + ((size_t)8 << 20));   // 8 MB (later y)
    unsigned short* xpT    = (unsigned short*)(wsb + ((size_t)16 << 20));  // 8 MB
    unsigned short* y = xb;  // xb dead after gemm1

    k_preA<<<384, 256, 0, stream>>>(x, in_w, out_w, xb, part_x, in_wb, out_wb);
    k_gemm<2><<<dim3(8, 32), 256, 0, stream>>>(xb, in_wb, in_b, xpT, part, part_x, xmean,
                                               Bv * Nv, Dv, Dv);
    k_mixg<<<dim3(4, 64), 512, 0, stream>>>(weight, xpT, bias, xmean, router_w, part, y,
                                            out + (size_t)Bv * Nv * Dv);
    k_gemm<0><<<dim3(8, 32), 256, 0, stream>>>(y, out_wb, out_b, out, nullptr, nullptr, nullptr,
                                               Bv * Nv, Dv, Dv);
}

// Round 13
// 73.752 us; speedup vs baseline: 1.1302x; 1.0971x over previous
//
#include <hip/hip_runtime.h>
#include <hip/hip_bf16.h>

#define Bv 8
#define Nv 512
#define Dv 1024
#define Ev 8
#define Hv 8
#define HDv 128
#define EPSv 1e-5f

typedef __attribute__((ext_vector_type(8))) short short8;
typedef __attribute__((ext_vector_type(4))) float f32x4;

__device__ __forceinline__ unsigned short f2b(float f) {
    __hip_bfloat16 h = __float2bfloat16(f);
    return *reinterpret_cast<unsigned short*>(&h);
}
__device__ __forceinline__ float bf2f(unsigned int u) {
    union { unsigned int i; float f; } v; v.i = u << 16; return v.f;
}

// async global->LDS, 16 bytes per lane; LDS dest must be linear (base + lane*16)
__device__ __forceinline__ void gld16(const void* g, void* l) {
    __builtin_amdgcn_global_load_lds(
        (const __attribute__((address_space(1))) void*)(uintptr_t)(g),
        (__attribute__((address_space(3))) void*)(uintptr_t)(l), 16, 0, 0);
}

// ---------------- preprocessing: only the small casts -----------------------
//   blocks [0,128):    cast x->bf16 + column partial sums
//   blocks [128,256):  cast in_w -> bf16
//   blocks [256,384):  cast out_w -> bf16
__global__ __launch_bounds__(256) void k_preA(const float* __restrict__ x,
                                              const float* __restrict__ w1,
                                              const float* __restrict__ w2,
                                              unsigned short* __restrict__ xb,
                                              float* __restrict__ part_x,
                                              unsigned short* __restrict__ w1b,
                                              unsigned short* __restrict__ w2b) {
    int bid = blockIdx.x;
    int t = threadIdx.x;
    if (bid < 128) {
        int b = bid >> 4, c = bid & 15;
        const float* px = x + ((size_t)b * Nv + c * 32) * Dv + t * 4;
        unsigned short* qx = xb + ((size_t)b * Nv + c * 32) * Dv + t * 4;
        float4 s4 = make_float4(0.f, 0.f, 0.f, 0.f);
        #pragma unroll 8
        for (int r = 0; r < 32; ++r) {
            float4 v = *(const float4*)(px + (size_t)r * Dv);
            s4.x += v.x; s4.y += v.y; s4.z += v.z; s4.w += v.w;
            uint2 pk;
            pk.x = (unsigned)f2b(v.x) | ((unsigned)f2b(v.y) << 16);
            pk.y = (unsigned)f2b(v.z) | ((unsigned)f2b(v.w) << 16);
            *(uint2*)(qx + (size_t)r * Dv) = pk;
        }
        *(float4*)(part_x + ((size_t)(b * 16 + c)) * Dv + t * 4) = s4;
        return;
    }
    const float* src; unsigned short* dst; int base;
    if (bid < 256) { src = w1; dst = w1b; base = (bid - 128) * 8192; }
    else           { src = w2; dst = w2b; base = (bid - 256) * 8192; }
    #pragma unroll
    for (int i = 0; i < 8; ++i) {
        float4 a = *(const float4*)(src + base + i * 1024 + t * 4);
        uint2 p;
        p.x = (unsigned)f2b(a.x) | ((unsigned)f2b(a.y) << 16);
        p.y = (unsigned)f2b(a.z) | ((unsigned)f2b(a.w) << 16);
        *(uint2*)(dst + base + i * 1024 + t * 4) = p;
    }
}

// ---------------- bf16 MFMA GEMM, depth-2 pipelined (3 LDS buffers) ---------
// MODE 0: C[m,n] = A[m,:].W[n,:] + bias[n], f32 out, normal layout
// MODE 2: bf16 out TRANSPOSED to Cv[b][n(d)][tok] (shape [Bv][Dv][Nv]) plus
//         per-(b,d) partial LN sums part[(b*Dv+d)*4 + m_chunk] = (sum, sumsq);
//         also reduces part_x -> xmean (overlapped with staging prologue)
template <int MODE>
__global__ __launch_bounds__(256) void k_gemm(
    const unsigned short* __restrict__ A,   // [M][K] bf16
    const unsigned short* __restrict__ W,   // [Nn][K] bf16
    const float* __restrict__ bias,         // [Nn] f32
    void* __restrict__ Cv,
    float2* __restrict__ part,
    const float* __restrict__ part_x,
    float* __restrict__ xmean,
    int M, int Nn, int K) {
    __shared__ __align__(16) unsigned short sA[3][128 * 64];
    __shared__ __align__(16) unsigned short sB[3][128 * 64];
    const int t = threadIdx.x;
    const int bn = blockIdx.x * 128;
    const int bm = blockIdx.y * 128;
    const int lane = t & 63;
    const int w = t >> 6, wm = w >> 1, wn = w & 1;
    const int fr = lane & 15, fq = lane >> 4;
    const int NT = K >> 6;
    f32x4 acc[4][4] = {};

#define STAGE(s, k0)                                                        \
    {                                                                       \
        _Pragma("unroll")                                                   \
        for (int i_ = 0; i_ < 4; ++i_) {                                    \
            int c_ = t + i_ * 256;                                          \
            int row_ = c_ >> 3, col_ = c_ & 7;                              \
            int cs_ = col_ ^ (row_ & 7);                                    \
            gld16(A + (size_t)(bm + row_) * K + (k0) + cs_ * 8, &sA[s][c_ * 8]); \
            gld16(W + (size_t)(bn + row_) * K + (k0) + cs_ * 8, &sB[s][c_ * 8]); \
        }                                                                   \
    }

    STAGE(0, 0);
    STAGE(1, 64);
    if (MODE == 2) {
        // xmean reduce: 256 blocks x 32 outputs, overlapped with async staging
        int blk = blockIdx.y * 8 + blockIdx.x;      // 0..255
        int o = blk * 32 + (t >> 3);                // output idx over 8192
        int c2 = t & 7;
        int b2 = o >> 10, d2 = o & 1023;
        float S = part_x[((size_t)(b2 * 16 + c2)) * Dv + d2]
                + part_x[((size_t)(b2 * 16 + c2 + 8)) * Dv + d2];
        S += __shfl_xor(S, 1); S += __shfl_xor(S, 2); S += __shfl_xor(S, 4);
        if (c2 == 0) xmean[o] = S * (1.f / Nv);
    }
    for (int it = 0; it < NT; ++it) {
        if (it + 2 < NT) {
            STAGE((it + 2) % 3, (it + 2) * 64);
            asm volatile("s_waitcnt vmcnt(16)" ::: "memory");
        } else if (it + 1 < NT) {
            asm volatile("s_waitcnt vmcnt(8)" ::: "memory");
        } else {
            asm volatile("s_waitcnt vmcnt(0)" ::: "memory");
        }
        __builtin_amdgcn_s_barrier();
        const unsigned short* pA = sA[it % 3];
        const unsigned short* pB = sB[it % 3];
        #pragma unroll
        for (int kk = 0; kk < 2; ++kk) {
            short8 af[4], bv[4];
            #pragma unroll
            for (int i = 0; i < 4; ++i)
                af[i] = *(const short8*)&pA[(wm * 64 + i * 16 + fr) * 64 + (((kk << 2) + fq) ^ (fr & 7)) * 8];
            #pragma unroll
            for (int j = 0; j < 4; ++j)
                bv[j] = *(const short8*)&pB[(wn * 64 + j * 16 + fr) * 64 + (((kk << 2) + fq) ^ (fr & 7)) * 8];
            #pragma unroll
            for (int i = 0; i < 4; ++i)
                #pragma unroll
                for (int j = 0; j < 4; ++j)
                    acc[i][j] = __builtin_amdgcn_mfma_f32_16x16x32_bf16(af[i], bv[j], acc[i][j], 0, 0, 0);
        }
        __builtin_amdgcn_s_barrier();
    }
#undef STAGE
    if (MODE == 0) {
        #pragma unroll
        for (int j = 0; j < 4; ++j) {
            const int n = bn + wn * 64 + j * 16 + fr;
            const float bj = bias[n];
            #pragma unroll
            for (int i = 0; i < 4; ++i) {
                const int m0 = bm + wm * 64 + i * 16 + fq * 4;
                #pragma unroll
                for (int r = 0; r < 4; ++r)
                    ((float*)Cv)[(size_t)(m0 + r) * Nn + n] = acc[i][j][r] + bj;
            }
        }
    } else {
        // ---- transposed bf16 tile via LDS (K-loop LDS is dead now) + stats ----
        unsigned short* sc = &sA[0][0];        // [128 d][136 tok] ushort = 34 KB
        float2* red = (float2*)&sB[0][0];      // [128 d][8] partial (s,q) = 8 KB
        const int bB   = bm >> 9;              // batch
        const int tok0 = bm & 511;             // token offset within batch
        const int chunk = (bm >> 7) & 3;       // which 128-token chunk
        #pragma unroll
        for (int j = 0; j < 4; ++j) {
            const int col = wn * 64 + j * 16 + fr;       // local d
            const float bj = bias[bn + col];
            float s = 0.f, q = 0.f;
            #pragma unroll
            for (int i = 0; i < 4; ++i) {
                const int row0 = wm * 64 + i * 16 + fq * 4;  // local token
                #pragma unroll
                for (int r = 0; r < 4; r += 2) {
                    float v0 = acc[i][j][r] + bj;
                    float v1 = acc[i][j][r + 1] + bj;
                    s += v0 + v1;
                    q = fmaf(v0, v0, fmaf(v1, v1, q));
                    unsigned int pk = (unsigned int)f2b(v0) | ((unsigned int)f2b(v1) << 16);
                    *(unsigned int*)&sc[col * 136 + row0 + r] = pk;
                }
            }
            red[col * 8 + wm * 4 + fq] = make_float2(s, q);
        }
        __syncthreads();
        if (t < 128) {
            float S = 0.f, Q = 0.f;
            #pragma unroll
            for (int k = 0; k < 8; ++k) { float2 v = red[t * 8 + k]; S += v.x; Q += v.y; }
            part[((size_t)bB * Dv + bn + t) * 4 + chunk] = make_float2(S, Q);
        }
        unsigned short* dst = (unsigned short*)Cv;
        #pragma unroll
        for (int k = 0; k < 8; ++k) {
            const int c = t + k * 256;
            const int dl = c >> 4, tk = c & 15;
            uint4 v = *(const uint4*)&sc[dl * 136 + tk * 8];
            *(uint4*)&dst[((size_t)bB * Dv + bn + dl) * Nv + tok0 + tk * 8] = v;
        }
    }
}

// ---------------- mixer GEMM: two-expert unnormalized-exp accumulation -----
//   acc_e[m,d] = sum_n exp(w_e[m,n]) * xp[d,n]   (A staged as raw exp, bf16)
//   s_e[m]     = sum_n exp(w_e[m,n])             (by-product of staging)
//   out = rstd_d*((tw0/s0[m])*acc0 + (tw1/s1[m])*acc1 - mu_d) + blended bias
// Weight is read EXACTLY ONCE per block (no phase A, no materialized wa).
// No max-subtraction: |w| <= 1/sqrt(512) so exp in [0.957, 1.045].
__global__ __launch_bounds__(256) void k_mixg(
    const float* __restrict__ weight,         // [E][H][512][512] f32 raw
    const unsigned short* __restrict__ xpT,   // [8][1024][512] bf16 (raw xp, transposed)
    const float* __restrict__ bias,           // [E][H][512] f32
    const float* __restrict__ xmean,          // [8][1024] f32
    const float* __restrict__ router_w,       // [E][1024] f32
    const float2* __restrict__ part,          // [(b*Dv+d)*4 + chunk] (sum,sumsq)
    unsigned short* __restrict__ y,           // [8][512][1024] bf16
    float* __restrict__ aux_out) {
    __shared__ __align__(16) unsigned short sA0[2][128 * 64];
    __shared__ __align__(16) unsigned short sA1[2][128 * 64];
    __shared__ __align__(16) unsigned short sB[2][128 * 64];
    __shared__ float rowc0[128], rowc1[128];
    __shared__ float probs[Bv][Ev];
    __shared__ float twsh[Bv][2];
    __shared__ int   tsel[Bv][2];
    __shared__ int   top1s[Bv];
    const int t = threadIdx.x;
    const int bm = blockIdx.x * 128;  // m tile (4)
    const int bh = blockIdx.y;        // 64
    const int b = bh >> 3, h = bh & 7;

    // ---- redundant per-block router: 64 dots (b,e) x 4 lanes each ----
    {
        int pid = t >> 2, l = t & 3;
        int rb = pid >> 3, re = pid & 7;
        const float4* xm = (const float4*)(xmean + rb * Dv);
        const float4* rw = (const float4*)(router_w + re * Dv);
        float s = 0.f;
        #pragma unroll
        for (int j = 0; j < 64; ++j) {
            float4 aa = xm[l + j * 4], ww = rw[l + j * 4];
            s = fmaf(aa.x, ww.x, s); s = fmaf(aa.y, ww.y, s);
            s = fmaf(aa.z, ww.z, s); s = fmaf(aa.w, ww.w, s);
        }
        s += __shfl_xor(s, 1); s += __shfl_xor(s, 2);
        if (l == 0) probs[rb][re] = s;
    }
    __syncthreads();
    if (t < Bv) {
        int bb = t;
        float mx = -1e30f;
        for (int e2 = 0; e2 < Ev; ++e2) mx = fmaxf(mx, probs[bb][e2]);
        float sum = 0.f;
        for (int e2 = 0; e2 < Ev; ++e2) { float v = __expf(probs[bb][e2] - mx); probs[bb][e2] = v; sum += v; }
        float inv = 1.f / sum;
        for (int e2 = 0; e2 < Ev; ++e2) probs[bb][e2] *= inv;
        int i0 = 0; float p0 = probs[bb][0];
        for (int e2 = 1; e2 < Ev; ++e2) if (probs[bb][e2] > p0) { p0 = probs[bb][e2]; i0 = e2; }
        int i1 = -1; float p1 = -1.f;
        for (int e2 = 0; e2 < Ev; ++e2) if (e2 != i0 && probs[bb][e2] > p1) { p1 = probs[bb][e2]; i1 = e2; }
        float s2 = p0 + p1;
        tsel[bb][0] = i0; tsel[bb][1] = i1;
        twsh[bb][0] = p0 / s2; twsh[bb][1] = p1 / s2;
        top1s[bb] = i0;
    }
    __syncthreads();
    if (blockIdx.x == 0 && bh == 0 && t == 0) {
        float aux = 0.f;
        for (int e2 = 0; e2 < Ev; ++e2) {
            float pm = 0.f, mm = 0.f;
            for (int bb = 0; bb < Bv; ++bb) { pm += probs[bb][e2]; mm += (top1s[bb] == e2) ? 1.f : 0.f; }
            aux += (pm / Bv) * (mm / Bv);
        }
        *aux_out = aux * Ev;
    }
    const int e0 = tsel[b][0], e1 = tsel[b][1];
    const float tw0 = twsh[b][0], tw1 = twsh[b][1];

    const int lane = t & 63;
    const int w = t >> 6, wm = w >> 1, wn = w & 1;
    const int fr = lane & 15, fq = lane >> 4;

    // ---- LN stats from gemm1 partials ----
    float rstd_j[4], nmr_j[4];
    #pragma unroll
    for (int j = 0; j < 4; ++j) {
        const int dg = h * HDv + wn * 64 + j * 16 + fr;
        const float2* pp = part + ((size_t)b * Dv + dg) * 4;
        float S = 0.f, Q = 0.f;
        #pragma unroll
        for (int cc = 0; cc < 4; ++cc) { float2 v = pp[cc]; S += v.x; Q += v.y; }
        float mu = S * (1.f / Nv);
        float var = Q * (1.f / Nv) - mu * mu;
        float rs = rsqrtf(var + EPSv);
        rstd_j[j] = rs; nmr_j[j] = -mu * rs;
    }

    const float* W0 = weight + (size_t)(e0 * Hv + h) * Nv * Nv;
    const float* W1 = weight + (size_t)(e1 * Hv + h) * Nv * Nv;
    const unsigned short* Bb = xpT + ((size_t)b * Dv + h * HDv) * Nv;

    const int NT = Nv >> 6;  // 8
    f32x4 acc0[4][4] = {}, acc1[4][4] = {};
    float4 ra0[4][2], ra1[4][2];
    float s0p[4] = {0.f, 0.f, 0.f, 0.f}, s1p[4] = {0.f, 0.f, 0.f, 0.f};

#define BSTAGE(s, k0)                                                       \
    {                                                                       \
        _Pragma("unroll")                                                   \
        for (int i_ = 0; i_ < 4; ++i_) {                                    \
            int c_ = t + i_ * 256;                                          \
            int row_ = c_ >> 3, col_ = c_ & 7;                              \
            int cs_ = col_ ^ (row_ & 7);                                    \
            gld16(Bb + (size_t)row_ * Nv + (k0) + cs_ * 8, &sB[s][c_ * 8]); \
        }                                                                   \
    }
#define ALOAD(k0)                                                           \
    {                                                                       \
        _Pragma("unroll")                                                   \
        for (int i_ = 0; i_ < 4; ++i_) {                                    \
            int c_ = t + i_ * 256;                                          \
            int row_ = c_ >> 3, col_ = c_ & 7;                              \
            int cs_ = col_ ^ (row_ & 7);                                    \
            size_t off_ = (size_t)(bm + row_) * Nv + (k0) + cs_ * 8;        \
            ra0[i_][0] = *(const float4*)&W0[off_];                         \
            ra0[i_][1] = *(const float4*)&W0[off_ + 4];                     \
            ra1[i_][0] = *(const float4*)&W1[off_];                         \
            ra1[i_][1] = *(const float4*)&W1[off_ + 4];                     \
        }                                                                   \
    }

    BSTAGE(0, 0);
    ALOAD(0);
    for (int it = 0; it < NT; ++it) {
        if (it + 1 < NT) {
            BSTAGE((it + 1) & 1, (it + 1) * 64);
            asm volatile("s_waitcnt vmcnt(4)" ::: "memory");
        } else {
            asm volatile("s_waitcnt vmcnt(0)" ::: "memory");
        }
        // exp-stage both experts -> LDS; accumulate per-thread row sums (f32)
        #pragma unroll
        for (int i = 0; i < 4; ++i) {
            int c = t + i * 256;
            float e0v[8], e1v[8];
            const float4 a0 = ra0[i][0], a1 = ra0[i][1];
            const float4 b0 = ra1[i][0], b1 = ra1[i][1];
            e0v[0] = __expf(a0.x); e0v[1] = __expf(a0.y);
            e0v[2] = __expf(a0.z); e0v[3] = __expf(a0.w);
            e0v[4] = __expf(a1.x); e0v[5] = __expf(a1.y);
            e0v[6] = __expf(a1.z); e0v[7] = __expf(a1.w);
            e1v[0] = __expf(b0.x); e1v[1] = __expf(b0.y);
            e1v[2] = __expf(b0.z); e1v[3] = __expf(b0.w);
            e1v[4] = __expf(b1.x); e1v[5] = __expf(b1.y);
            e1v[6] = __expf(b1.z); e1v[7] = __expf(b1.w);
            s0p[i] += ((e0v[0] + e0v[1]) + (e0v[2] + e0v[3]))
                    + ((e0v[4] + e0v[5]) + (e0v[6] + e0v[7]));
            s1p[i] += ((e1v[0] + e1v[1]) + (e1v[2] + e1v[3]))
                    + ((e1v[4] + e1v[5]) + (e1v[6] + e1v[7]));
            uint4 p0, p1;
            p0.x = (unsigned)f2b(e0v[0]) | ((unsigned)f2b(e0v[1]) << 16);
            p0.y = (unsigned)f2b(e0v[2]) | ((unsigned)f2b(e0v[3]) << 16);
            p0.z = (unsigned)f2b(e0v[4]) | ((unsigned)f2b(e0v[5]) << 16);
            p0.w = (unsigned)f2b(e0v[6]) | ((unsigned)f2b(e0v[7]) << 16);
            p1.x = (unsigned)f2b(e1v[0]) | ((unsigned)f2b(e1v[1]) << 16);
            p1.y = (unsigned)f2b(e1v[2]) | ((unsigned)f2b(e1v[3]) << 16);
            p1.z = (unsigned)f2b(e1v[4]) | ((unsigned)f2b(e1v[5]) << 16);
            p1.w = (unsigned)f2b(e1v[6]) | ((unsigned)f2b(e1v[7]) << 16);
            *(uint4*)&sA0[it & 1][c * 8] = p0;
            *(uint4*)&sA1[it & 1][c * 8] = p1;
        }
        if (it + 1 < NT) ALOAD((it + 1) * 64);
        asm volatile("s_waitcnt lgkmcnt(0)" ::: "memory");
        __builtin_amdgcn_s_barrier();
        const unsigned short* pA0 = sA0[it & 1];
        const unsigned short* pA1 = sA1[it & 1];
        const unsigned short* pB = sB[it & 1];
        #pragma unroll
        for (int kk = 0; kk < 2; ++kk) {
            short8 bv[4];
            #pragma unroll
            for (int j = 0; j < 4; ++j)
                bv[j] = *(const short8*)&pB[(wn * 64 + j * 16 + fr) * 64 + (((kk << 2) + fq) ^ (fr & 7)) * 8];
            #pragma unroll
            for (int i = 0; i < 4; ++i) {
                const int aoff = (wm * 64 + i * 16 + fr) * 64 + (((kk << 2) + fq) ^ (fr & 7)) * 8;
                short8 af0 = *(const short8*)&pA0[aoff];
                short8 af1 = *(const short8*)&pA1[aoff];
                #pragma unroll
                for (int j = 0; j < 4; ++j)
                    acc0[i][j] = __builtin_amdgcn_mfma_f32_16x16x32_bf16(af0, bv[j], acc0[i][j], 0, 0, 0);
                #pragma unroll
                for (int j = 0; j < 4; ++j)
                    acc1[i][j] = __builtin_amdgcn_mfma_f32_16x16x32_bf16(af1, bv[j], acc1[i][j], 0, 0, 0);
            }
        }
        __builtin_amdgcn_s_barrier();
    }
#undef BSTAGE
#undef ALOAD

    // ---- finalize row sums: reduce over the 8 lanes sharing each row, ----
    // ---- store normalization coefficients to LDS ----
    #pragma unroll
    for (int i = 0; i < 4; ++i) {
        #pragma unroll
        for (int off = 1; off < 8; off <<= 1) {
            s0p[i] += __shfl_xor(s0p[i], off);
            s1p[i] += __shfl_xor(s1p[i], off);
        }
        int row = (t >> 3) + i * 32;   // == (t + i*256) >> 3
        if ((t & 7) == 0) {
            rowc0[row] = tw0 / s0p[i];
            rowc1[row] = tw1 / s1p[i];
        }
    }
    __syncthreads();

    // ---- epilogue: y = rstd_d*(c0*acc0 + c1*acc1 - mu_d) + blended bias ----
    #pragma unroll
    for (int i = 0; i < 4; ++i) {
        #pragma unroll
        for (int r = 0; r < 4; ++r) {
            const int ml = wm * 64 + i * 16 + fq * 4 + r;
            const int m = bm + ml;
            const float c0m = rowc0[ml], c1m = rowc1[ml];
            const float br = tw0 * bias[(size_t)(e0 * Hv + h) * Nv + m]
                           + tw1 * bias[(size_t)(e1 * Hv + h) * Nv + m];
            #pragma unroll
            for (int j = 0; j < 4; ++j) {
                const int d = wn * 64 + j * 16 + fr;
                float vb = c0m * acc0[i][j][r] + c1m * acc1[i][j][r];
                float v = fmaf(vb, rstd_j[j], nmr_j[j] + br);
                y[((size_t)b * Nv + m) * Dv + h * HDv + d] = f2b(v);
            }
        }
    }
}

extern "C" void kernel_launch(void* const* d_in, const int* in_sizes, int n_in,
                              void* d_out, int out_size, void* d_ws, size_t ws_size,
                              hipStream_t stream) {
    const float* x        = (const float*)d_in[0];
    const float* weight   = (const float*)d_in[1];
    const float* bias     = (const float*)d_in[2];
    const float* router_w = (const float*)d_in[3];
    const float* in_w     = (const float*)d_in[4];
    const float* in_b     = (const float*)d_in[5];
    const float* out_w    = (const float*)d_in[6];
    const float* out_b    = (const float*)d_in[7];
    float* out = (float*)d_out;

    if (ws_size < ((size_t)63 << 20)) return;

    char* wsb = (char*)d_ws;
    float*  xmean  = (float*)(wsb);                                  // 32 KB
    float2* part   = (float2*)(wsb + (64 << 10));                    // 256 KB
    float*  part_x = (float*)(wsb + (512 << 10));                    // 512 KB
    unsigned short* in_wb  = (unsigned short*)(wsb + ((size_t)2 << 20));   // 2 MB
    unsigned short* out_wb = (unsigned short*)(wsb + ((size_t)4 << 20));   // 2 MB
    unsigned short* xb     = (unsigned short*)(wsb + ((size_t)8 << 20));   // 8 MB (later y)
    unsigned short* xpT    = (unsigned short*)(wsb + ((size_t)16 << 20));  // 8 MB
    unsigned short* y = xb;  // xb dead after gemm1

    k_preA<<<384, 256, 0, stream>>>(x, in_w, out_w, xb, part_x, in_wb, out_wb);
    k_gemm<2><<<dim3(8, 32), 256, 0, stream>>>(xb, in_wb, in_b, xpT, part, part_x, xmean,
                                               Bv * Nv, Dv, Dv);
    k_mixg<<<dim3(4, 64), 256, 0, stream>>>(weight, xpT, bias, xmean, router_w, part, y,
                                            out + (size_t)Bv * Nv * Dv);
    k_gemm<0><<<dim3(8, 32), 256, 0, stream>>>(y, out_wb, out_b, out, nullptr, nullptr, nullptr,
                                               Bv * Nv, Dv, Dv);
}